// Round 1
// baseline (345.118 us; speedup 1.0000x reference)
//
#include <hip/hip_runtime.h>
#include <math.h>

// GridNeRF fused hierarchical sampling + volume rendering.
// N=65536 rays, NC=64 coarse, NF=128 fine, S=192 combined samples.
// One wave (64 lanes) per ray; 4 rays per 256-thread block; no __syncthreads
// (all LDS is wave-private slices, program order within a wave suffices).
//
// Sort strategy (R2): combined sort == merge of two sorted lists.
//  - coarse_t is sorted by construction (stratified bins).
//  - sorting the 128 u's (bitonic, 2 regs/lane, 28 stages) makes fine_t
//    sorted, since fine_t = Finv(u) with Finv monotone.
//  - merge ranks from the CDF: rank(coarse i) = i + #{u < cdf[i]},
//    rank(fine j) = j + pos_j + 1  (pos_j = searchsorted bin, needed for the
//    interpolation anyway). Exact stable-merge bijection -> collision-free
//    LDS scatter materializes the sorted t array.
//  - cdf forced monotone via a max-scan so the bijection is exact under FP.
//
// R3 (this round): issue-bound polish.
//  - phase 5 restructured 4 samples x 48 lanes -> 3 samples x 64 lanes
//    (wave-instruction count is what VALU pays, not active lanes);
//    col/den/fine_points move as dwordx3, still unit-stride coalesced.
//  - expf -> __expf (v_exp_f32), one exp feeds both alpha and 1-alpha+eps.
//  - col/den/ro/rd prefetched at kernel entry (after cw/ct/uu so their
//    waitcnt doesn't drain the prefetch) to spread HBM demand across the
//    whole wave lifetime instead of bursting after the sort.

#define NRAYS 65536
#define NCC   64
#define NFF   128
#define SS    192

struct f3 { float x, y, z; };   // 12 B, align 4 -> global_load/store_dwordx3

__global__ __launch_bounds__(256)
void nerf_fused(const float* __restrict__ ro,  const float* __restrict__ rd,
                const float* __restrict__ cw,  const float* __restrict__ ct,
                const float* __restrict__ uu,  const float* __restrict__ col,
                const float* __restrict__ den, float* __restrict__ out)
{
    const int lane = threadIdx.x & 63;
    const int wv   = threadIdx.x >> 6;
    const int ray  = blockIdx.x * 4 + wv;

    __shared__ float s_cdf[4][65];    // cdf[0..64] (monotone)
    __shared__ float s_ct [4][64];    // coarse t
    __shared__ float s_su [4][128];   // sorted u
    __shared__ float s_vals[4][192];  // scatter target: sorted combined t

    // ---------- issue ALL global loads up front ----------
    // phase-1/2 inputs first: their waitcnts drain first and leave the
    // phase-5 prefetches (den/col/ro/rd) in flight under the sort.
    float wt = cw[(size_t)ray * NCC + lane] + 1e-5f;
    float tc = ct[(size_t)ray * NCC + lane];
    float2 u2 = *(const float2*)(uu + (size_t)ray * NFF + 2 * lane);
    // phase-5 prefetch (3 samples per lane: s = 3*lane + r)
    float dx = rd[(size_t)ray * 3 + 0], dy = rd[(size_t)ray * 3 + 1], dz = rd[(size_t)ray * 3 + 2];
    float ox = ro[(size_t)ray * 3 + 0], oy = ro[(size_t)ray * 3 + 1], oz = ro[(size_t)ray * 3 + 2];
    f3 dn = *(const f3*)(den + (size_t)ray * SS + 3 * lane);
    const float* cp = col + (size_t)ray * (SS * 3) + 9 * lane;
    f3 c0 = *(const f3*)(cp + 0);
    f3 c1 = *(const f3*)(cp + 3);
    f3 c2 = *(const f3*)(cp + 6);

    // ---------- Phase 1: weights -> normalized monotone cdf ----------
    float x = wt;
    #pragma unroll
    for (int off = 1; off < 64; off <<= 1) {
        float y = __shfl_up(x, off);
        if (lane >= off) x += y;
    }
    float total = __shfl(x, 63);
    float cv = x / total;
    // max-scan: enforce non-decreasing cdf (rank-scatter bijection guard)
    #pragma unroll
    for (int off = 1; off < 64; off <<= 1) {
        float y = __shfl_up(cv, off);
        if (lane >= off) cv = fmaxf(cv, y);
    }
    s_cdf[wv][lane + 1] = cv;
    if (lane == 0) s_cdf[wv][0] = 0.0f;
    s_ct[wv][lane] = tc;

    // ---------- Phase 2: bitonic sort of the 128 u's (2 regs/lane) ----------
    float v0 = u2.x, v1 = u2.y;   // elements 2*lane, 2*lane+1
    #pragma unroll
    for (int k = 2; k <= 128; k <<= 1) {
        #pragma unroll
        for (int j = k >> 1; j >= 1; j >>= 1) {
            bool up = (((lane << 1) & k) == 0);   // same for both regs (k>=2)
            if (j == 1) {
                float a = v0, b = v1;
                v0 = up ? fminf(a, b) : fmaxf(a, b);
                v1 = up ? fmaxf(a, b) : fminf(a, b);
            } else {
                int m = j >> 1;                   // partner-lane xor mask
                bool keepmin = (((lane & m) == 0) == up);
                float p0 = __shfl_xor(v0, m);
                float p1 = __shfl_xor(v1, m);
                v0 = keepmin ? fminf(v0, p0) : fmaxf(v0, p0);
                v1 = keepmin ? fminf(v1, p1) : fmaxf(v1, p1);
            }
        }
    }
    *(float2*)&s_su[wv][2 * lane] = make_float2(v0, v1);

    // ---------- Phase 3: fine t from sorted u + scatter by merge rank ----------
    const float* cdfp = s_cdf[wv];
    const float* ctp  = s_ct[wv];
    float us[2] = {v0, v1};
    #pragma unroll
    for (int q = 0; q < 2; ++q) {
        float u = us[q];
        // pos = max{j in [0,63]: cdf[j] <= u}  (branchless descent)
        int pos = 0;
        #pragma unroll
        for (int st = 32; st >= 1; st >>= 1) {
            int np = pos + st;                 // np in [1,63]
            pos = (cdfp[np] <= u) ? np : pos;
        }
        int above = (pos + 1 < 63) ? (pos + 1) : 63;
        float cb = cdfp[pos], ca = cdfp[above];
        float tb = ctp[pos],  ta = ctp[above];
        float dnm = ca - cb;
        dnm = (dnm < 1e-5f) ? 1.0f : dnm;
        float tt = (u - cb) / dnm;
        float fval = tb + tt * (ta - tb);
        int rank = 2 * lane + q + pos + 1;     // j + #{coarse <= u_j}
        s_vals[wv][rank] = fval;
    }

    // ---------- Phase 4: coarse merge rank + scatter ----------
    const float* sup = s_su[wv];
    float key = cdfp[lane];                    // cdf[i], i = lane
    int cnt = 0;                               // #{u < cdf[i]}
    #pragma unroll
    for (int st = 128; st >= 1; st >>= 1) {
        int np = cnt + st;
        bool ok = (np <= 128) && (sup[np - 1] < key);
        cnt = ok ? np : cnt;
    }
    s_vals[wv][lane + cnt] = tc;

    // ---------- Phase 5: volume rendering, 3 samples/lane, all 64 lanes ----------
    float v0s = s_vals[wv][3 * lane + 0];
    float v1s = s_vals[wv][3 * lane + 1];
    float v2s = s_vals[wv][3 * lane + 2];

    float nrm = sqrtf(dx * dx + dy * dy + dz * dz);

    float tnext = __shfl_down(v0s, 1);         // t[3(l+1)]
    float d0 = v1s - v0s;
    float d1 = v2s - v1s;
    float d2 = (lane == 63) ? 1e10f : (tnext - v2s);

    // e = exp(-den*dist); alpha = 1-e; trans factor = 1-alpha+1e-10 = e+1e-10
    float e0 = __expf(-dn.x * (d0 * nrm));
    float e1 = __expf(-dn.y * (d1 * nrm));
    float e2 = __expf(-dn.z * (d2 * nrm));
    float a0 = 1.0f - e0, a1 = 1.0f - e1, a2 = 1.0f - e2;
    float f0 = e0 + 1e-10f, f1 = e1 + 1e-10f, f2 = e2 + 1e-10f;

    // fine_points = origin + dir * t (sorted order): 9 contiguous floats/lane
    {
        float* fp = out + (size_t)5 * NRAYS + (size_t)ray * (SS * 3) + 9 * lane;
        f3 p0 = {ox + dx * v0s, oy + dy * v0s, oz + dz * v0s};
        f3 p1 = {ox + dx * v1s, oy + dy * v1s, oz + dz * v1s};
        f3 p2 = {ox + dx * v2s, oy + dy * v2s, oz + dz * v2s};
        ((f3*)fp)[0] = p0;
        ((f3*)fp)[1] = p1;
        ((f3*)fp)[2] = p2;
    }

    // exclusive cumprod of (1-alpha+1e-10) over 192: in-lane prefix + wave scan
    float pr1 = f0, pr2 = f0 * f1;
    float sx = pr2 * f2;
    #pragma unroll
    for (int off = 1; off < 64; off <<= 1) {
        float y = __shfl_up(sx, off);
        if (lane >= off) sx *= y;
    }
    float excl = __shfl_up(sx, 1);
    if (lane == 0) excl = 1.0f;
    float w0 = a0 * excl;
    float w1 = a1 * (excl * pr1);
    float w2 = a2 * (excl * pr2);

    float rr  = w0 * c0.x + w1 * c1.x + w2 * c2.x;
    float gg  = w0 * c0.y + w1 * c1.y + w2 * c2.y;
    float bb  = w0 * c0.z + w1 * c1.z + w2 * c2.z;
    float dep = w0 * v0s + w1 * v1s + w2 * v2s;
    float opa = w0 + w1 + w2;

    #pragma unroll
    for (int off = 32; off >= 1; off >>= 1) {
        rr  += __shfl_xor(rr,  off);
        gg  += __shfl_xor(gg,  off);
        bb  += __shfl_xor(bb,  off);
        dep += __shfl_xor(dep, off);
        opa += __shfl_xor(opa, off);
    }
    if (lane == 0) {
        out[(size_t)ray * 3 + 0] = rr;
        out[(size_t)ray * 3 + 1] = gg;
        out[(size_t)ray * 3 + 2] = bb;
        out[(size_t)3 * NRAYS + ray] = dep;
        out[(size_t)4 * NRAYS + ray] = opa;
    }
}

extern "C" void kernel_launch(void* const* d_in, const int* in_sizes, int n_in,
                              void* d_out, int out_size, void* d_ws, size_t ws_size,
                              hipStream_t stream) {
    const float* ro  = (const float*)d_in[0];
    const float* rd  = (const float*)d_in[1];
    const float* cw  = (const float*)d_in[2];
    const float* ct  = (const float*)d_in[3];
    const float* uu  = (const float*)d_in[4];
    const float* col = (const float*)d_in[5];
    const float* den = (const float*)d_in[6];
    float* out = (float*)d_out;
    (void)in_sizes; (void)n_in; (void)out_size; (void)d_ws; (void)ws_size;
    nerf_fused<<<NRAYS / 4, 256, 0, stream>>>(ro, rd, cw, ct, uu, col, den, out);
}